// Round 12
// baseline (85.444 us; speedup 1.0000x reference)
//
#include <hip/hip_runtime.h>
#include <math.h>

#define N0 2048
#define N1 1024
#define M0T 32                     // 2048 / 64-row tiles
#define M1T 32                     // 1024 / 32-row tiles
#define NB0 (M0T * (M0T + 1) / 2)  // 528 lower-tri tile pairs, layer 0 (64x64)
#define NB1 (M1T * (M1T + 1) / 2)  // 528 lower-tri tile pairs, layer 1 (32x32)
#define NBTOT (NB0 + NB1)          // 1056 blocks
#define REPS 4                     // DIAGNOSTIC: 4x compute phase (rep0 = real)

// ws layout (floats): partial[NBTOT] only.
//
// Ledger:
// R1: same-address atomics+fence serialize -> separate finalize. (Counter row
//     atomic-poisoned; VALU work ~5.3us.)
// R2/R4: window = fill(39.5 fixed) + ~26us controllable. Dispatch-count
//     changes NET ZERO.
// R7: un-split + drop 5x5 Newton: 69.9 -> 65.4. absmax 0.
// R9: coop single-kernel FAILED absmax: plain stores not XCD-coherent even
//     with fence+grid.sync. Kernel boundary IS the flush.
// R10: launch_bounds(256,2)+prep wave-split: NULL (65.65).
// R11: padded LDS (12/28) + b128 + pinned a-regs + lb(256,4): NULL (65.01).
//     THREE nulls on pairs internals; solved system says pairs ~17-19us vs
//     ~5-6us VALU floor; mechanism unknown; pairs counters NEVER SEEN (below
//     fill's 39.5 top-5 cutoff).
// R12 (this): DIAGNOSTIC. REPS=4 on the compute phase; rep0 bit-identical ->
//     contrib; reps1-3 -> dummy (asm-kept-alive, v-order permuted per rep so
//     LICM can't merge). Pairs rises above fill cutoff -> counters visible;
//     delta_total = 3 x T_compute. Predict total 100-113 if compute-bound,
//     75-85 if prep/boundary-bound; absmax 0.
//     Pre-committed read: VALUBusy>=55 -> issue-bound (algorithmic/accept);
//     <=30 + low occ -> latency-bound (128-thread blocks next); conflicts
//     high -> bank fix; small delta -> stall outside compute phase.

__device__ __forceinline__ void tri_decode(int t, int& bi, int& bj) {
    int b = (int)((sqrtf(8.0f * t + 1.0f) - 1.0f) * 0.5f);
    while ((b + 1) * (b + 2) / 2 <= t) ++b;
    while (b * (b + 1) / 2 > t) --b;
    bi = b;
    bj = t - b * (b + 1) / 2;
}

// normalize + adjugate inverse + 1 Newton polish, 3x3, fp32
__device__ __forceinline__ void inv3_to(const float* __restrict__ g, float* __restrict__ dst) {
    float a[9];
    float ss = 0.0f;
#pragma unroll
    for (int e = 0; e < 9; ++e) { a[e] = g[e]; ss = fmaf(a[e], a[e], ss); }
    float rn = 1.0f / (sqrtf(ss) + 1e-8f);
#pragma unroll
    for (int e = 0; e < 9; ++e) a[e] *= rn;
    float c00 = a[4] * a[8] - a[5] * a[7];
    float c01 = -(a[3] * a[8] - a[5] * a[6]);
    float c02 = a[3] * a[7] - a[4] * a[6];
    float det = a[0] * c00 + a[1] * c01 + a[2] * c02;
    float id = 1.0f / det;
    float x[9];
    x[0] = c00 * id;
    x[1] = (a[2] * a[7] - a[1] * a[8]) * id;
    x[2] = (a[1] * a[5] - a[2] * a[4]) * id;
    x[3] = c01 * id;
    x[4] = (a[0] * a[8] - a[2] * a[6]) * id;
    x[5] = (a[2] * a[3] - a[0] * a[5]) * id;
    x[6] = c02 * id;
    x[7] = (a[1] * a[6] - a[0] * a[7]) * id;
    x[8] = (a[0] * a[4] - a[1] * a[3]) * id;
    // Newton polish: x <- x(2I - a x)
    float r[9];
#pragma unroll
    for (int i = 0; i < 3; ++i)
#pragma unroll
        for (int j = 0; j < 3; ++j) {
            float m = a[i * 3 + 0] * x[0 * 3 + j];
            m = fmaf(a[i * 3 + 1], x[1 * 3 + j], m);
            m = fmaf(a[i * 3 + 2], x[2 * 3 + j], m);
            r[i * 3 + j] = ((i == j) ? 2.0f : 0.0f) - m;
        }
#pragma unroll
    for (int i = 0; i < 3; ++i)
#pragma unroll
        for (int j = 0; j < 3; ++j) {
            float m = x[i * 3 + 0] * r[0 * 3 + j];
            m = fmaf(x[i * 3 + 1], r[1 * 3 + j], m);
            m = fmaf(x[i * 3 + 2], r[2 * 3 + j], m);
            dst[i * 3 + j] = m;
        }
}

// normalize only, 3x3
__device__ __forceinline__ void norm3_to(const float* __restrict__ g, float* __restrict__ dst) {
    float a[9];
    float ss = 0.0f;
#pragma unroll
    for (int e = 0; e < 9; ++e) { a[e] = g[e]; ss = fmaf(a[e], a[e], ss); }
    float rn = 1.0f / (sqrtf(ss) + 1e-8f);
#pragma unroll
    for (int e = 0; e < 9; ++e) dst[e] = a[e] * rn;
}

// normalize + branchless GJ w/ partial pivot, 5x5, fp32 (no Newton; R7-verified)
__device__ __forceinline__ void inv5_to(const float* __restrict__ g, float* __restrict__ dst) {
    float A[5][5], B[5][5];
    float ss = 0.0f;
#pragma unroll
    for (int r = 0; r < 5; ++r)
#pragma unroll
        for (int c = 0; c < 5; ++c) {
            float v = g[r * 5 + c];
            A[r][c] = v;
            ss = fmaf(v, v, ss);
        }
    float rn = 1.0f / (sqrtf(ss) + 1e-8f);
#pragma unroll
    for (int r = 0; r < 5; ++r)
#pragma unroll
        for (int c = 0; c < 5; ++c) {
            A[r][c] *= rn;
            B[r][c] = (r == c) ? 1.0f : 0.0f;
        }
#pragma unroll
    for (int k = 0; k < 5; ++k) {
#pragma unroll
        for (int r = k + 1; r < 5; ++r) {
            bool sw = fabsf(A[r][k]) > fabsf(A[k][k]);
#pragma unroll
            for (int c = k; c < 5; ++c) {
                float Ar = A[r][c], Ak = A[k][c];
                A[r][c] = sw ? Ak : Ar;
                A[k][c] = sw ? Ar : Ak;
            }
#pragma unroll
            for (int c = 0; c < 5; ++c) {
                float Br = B[r][c], Bk = B[k][c];
                B[r][c] = sw ? Bk : Br;
                B[k][c] = sw ? Br : Bk;
            }
        }
        float piv = 1.0f / A[k][k];
#pragma unroll
        for (int c = k; c < 5; ++c) A[k][c] *= piv;
#pragma unroll
        for (int c = 0; c < 5; ++c) B[k][c] *= piv;
#pragma unroll
        for (int r = 0; r < 5; ++r) {
            if (r == k) continue;
            float f = A[r][k];
#pragma unroll
            for (int c = k; c < 5; ++c) A[r][c] = fmaf(-f, A[k][c], A[r][c]);
#pragma unroll
            for (int c = 0; c < 5; ++c) B[r][c] = fmaf(-f, B[k][c], B[r][c]);
        }
    }
#pragma unroll
    for (int r = 0; r < 5; ++r)
#pragma unroll
        for (int c = 0; c < 5; ++c) dst[r * 5 + c] = B[r][c];
}

// normalize only, 5x5
__device__ __forceinline__ void norm5_to(const float* __restrict__ g, float* __restrict__ dst) {
    float a[25];
    float ss = 0.0f;
#pragma unroll
    for (int e = 0; e < 25; ++e) { a[e] = g[e]; ss = fmaf(a[e], a[e], ss); }
    float rn = 1.0f / (sqrtf(ss) + 1e-8f);
#pragma unroll
    for (int e = 0; e < 25; ++e) dst[e] = a[e] * rn;
}

// ---------------------------------------------------------------------------
// R11 structure + REPS=4 diagnostic on the compute phase.
// rep 0: vv == v, accumulates into contrib (bit-identical to R11).
// reps 1-3: v-order rotated ((v+rep)&mask), accumulate into dummy, kept
// alive by asm volatile (prevents DCE, rule #17) and un-hoistable (LICM
// can't merge reps since the load order differs).
// ---------------------------------------------------------------------------
__global__ __launch_bounds__(256, 4) void pairs_kernel(const float* __restrict__ k0,
                                                       const float* __restrict__ k1,
                                                       float* __restrict__ partial) {
    __shared__ __align__(16) float sA[896];  // L0: 64*12=768, L1: 32*28=896
    __shared__ __align__(16) float sB[896];
    int tid = threadIdx.x;
    float contrib = 0.0f;
    float dummy = 0.0f;

    if (blockIdx.x < NB0) {
        // ---------------- layer 0: d=3, 64x64, stride 12 ----------------
        int bi, bj;
        tri_decode(blockIdx.x, bi, bj);

        if (tid < 64) {
            inv3_to(k0 + (bi * 64 + tid) * 9, sA + tid * 12);
        } else if (tid < 128) {
            int j = tid - 64;
            norm3_to(k0 + (bj * 64 + j) * 9, sB + j * 12);
        }
        __syncthreads();

        int ti = tid >> 4, tj = tid & 15;
        int ibase = bi * 64 + ti * 4, jbase = bj * 64 + tj * 4;
        float a[4][12];
#pragma unroll
        for (int u = 0; u < 4; ++u) {
            float4* d = (float4*)a[u];
            const float4* s = (const float4*)(sA + (ti * 4 + u) * 12);
            d[0] = s[0]; d[1] = s[1]; d[2] = s[2];
        }
        __builtin_amdgcn_sched_barrier(0);  // pin preload: a[][] live across loop
#pragma unroll 1
        for (int rep = 0; rep < REPS; ++rep) {
            float c = 0.0f;
#pragma unroll
            for (int v = 0; v < 4; ++v) {
                int vv = (v + rep) & 3;
                float b[12];
                {
                    float4* d = (float4*)b;
                    const float4* s = (const float4*)(sB + (tj * 4 + vv) * 12);
                    d[0] = s[0]; d[1] = s[1]; d[2] = s[2];
                }
#pragma unroll
                for (int u = 0; u < 4; ++u) {
                    float s = 0.0f;
#pragma unroll
                    for (int r = 0; r < 3; ++r)
#pragma unroll
                        for (int cc = 0; cc < 3; ++cc) {
                            float m = a[u][r * 3 + 0] * b[cc];
                            m = fmaf(a[u][r * 3 + 1], b[3 + cc], m);
                            m = fmaf(a[u][r * 3 + 2], b[6 + cc], m);
                            float d = ((r == cc) ? 1.0f : 0.0f) - m;
                            s = fmaf(d, d, s);
                        }
                    bool take = ((ibase + u) > (jbase + vv)) && (s < 1.0f);
                    c += take ? (1.0f - __builtin_amdgcn_sqrtf(s)) : 0.0f;
                }
            }
            if (rep == 0) contrib += c; else dummy += c;
        }
    } else {
        // ---------------- layer 1: d=5, 32x32, stride 28 ----------------
        int bi, bj;
        tri_decode(blockIdx.x - NB0, bi, bj);

        if (tid < 32) {
            inv5_to(k1 + (bi * 32 + tid) * 25, sA + tid * 28);
        } else if (tid < 64) {
            int j = tid - 32;
            norm5_to(k1 + (bj * 32 + j) * 25, sB + j * 28);
        }
        __syncthreads();

        int ti = tid >> 4, tj = tid & 15;
        int ibase = bi * 32 + ti * 2, jbase = bj * 32 + tj * 2;
        float a[2][28];
#pragma unroll
        for (int u = 0; u < 2; ++u) {
            float4* d = (float4*)a[u];
            const float4* s = (const float4*)(sA + (ti * 2 + u) * 28);
#pragma unroll
            for (int q = 0; q < 7; ++q) d[q] = s[q];
        }
        __builtin_amdgcn_sched_barrier(0);  // pin preload: a[][] live across loop
#pragma unroll 1
        for (int rep = 0; rep < REPS; ++rep) {
            float c = 0.0f;
#pragma unroll
            for (int v = 0; v < 2; ++v) {
                int vv = (v + rep) & 1;
                float b[28];
                {
                    float4* d = (float4*)b;
                    const float4* s = (const float4*)(sB + (tj * 2 + vv) * 28);
#pragma unroll
                    for (int q = 0; q < 7; ++q) d[q] = s[q];
                }
#pragma unroll
                for (int u = 0; u < 2; ++u) {
                    float s = 0.0f;
#pragma unroll
                    for (int r = 0; r < 5; ++r)
#pragma unroll
                        for (int cc = 0; cc < 5; ++cc) {
                            float m = a[u][r * 5 + 0] * b[cc];
#pragma unroll
                            for (int k = 1; k < 5; ++k) m = fmaf(a[u][r * 5 + k], b[k * 5 + cc], m);
                            float d = ((r == cc) ? 1.0f : 0.0f) - m;
                            s = fmaf(d, d, s);
                        }
                    bool take = ((ibase + u) > (jbase + vv)) && (s < 1.0f);
                    c += take ? (1.0f - __builtin_amdgcn_sqrtf(s)) : 0.0f;
                }
            }
            if (rep == 0) contrib += c; else dummy += c;
        }
    }

    // keep reps 1-3 alive without cost (no DCE) -- diagnostic only
    asm volatile("" : : "v"(dummy));

    // block reduction -> one partial per block, distinct address (no contention)
#pragma unroll
    for (int off = 32; off; off >>= 1) contrib += __shfl_down(contrib, off);
    __shared__ float wsum[4];
    if ((tid & 63) == 0) wsum[tid >> 6] = contrib;
    __syncthreads();
    if (tid == 0) partial[blockIdx.x] = wsum[0] + wsum[1] + wsum[2] + wsum[3];
}

__global__ void finalize_kernel(const float* __restrict__ partial, float* __restrict__ out) {
    int tid = threadIdx.x;
    double s0 = 0.0, s1 = 0.0;
    for (int x = tid; x < NB0; x += 256) s0 += (double)partial[x];
    for (int x = NB0 + tid; x < NBTOT; x += 256) s1 += (double)partial[x];
#pragma unroll
    for (int off = 32; off; off >>= 1) {
        s0 += __shfl_down(s0, off);
        s1 += __shfl_down(s1, off);
    }
    __shared__ double w0[4], w1[4];
    if ((tid & 63) == 0) { w0[tid >> 6] = s0; w1[tid >> 6] = s1; }
    __syncthreads();
    if (tid == 0) {
        double S0 = w0[0] + w0[1] + w0[2] + w0[3];
        double S1 = w1[0] + w1[1] + w1[2] + w1[3];
        // final = (2*S0/(n0(n0-1)) + 2*S1/(n1(n1-1))) / 2
        double res = S0 / ((double)N0 * (double)(N0 - 1)) +
                     S1 / ((double)N1 * (double)(N1 - 1));
        out[0] = (float)res;
    }
}

extern "C" void kernel_launch(void* const* d_in, const int* in_sizes, int n_in,
                              void* d_out, int out_size, void* d_ws, size_t ws_size,
                              hipStream_t stream) {
    const float* k0 = (const float*)d_in[0];  // (2048,3,3)
    const float* k1 = (const float*)d_in[1];  // (1024,5,5)
    float* out = (float*)d_out;

    float* partial = (float*)d_ws;  // 1056 floats

    pairs_kernel<<<NBTOT, 256, 0, stream>>>(k0, k1, partial);
    finalize_kernel<<<1, 256, 0, stream>>>(partial, out);
}

// Round 20
// 65.457 us; speedup vs baseline: 1.3053x; 1.3053x over previous
//
#include <hip/hip_runtime.h>
#include <math.h>

#define N0 2048
#define N1 1024
#define M0T 32                      // 2048 / 64-row tiles
#define M1T 32                      // 1024 / 32-row tiles
#define NBP 272                     // paired-column blocks per layer: sum ceil((bi+1)/2)
#define NBTOTP (2 * NBP)            // 544 blocks total

// ws layout (floats): partial[NBTOTP] only.
//
// Ledger:
// R1: same-address atomics+fence serialize -> separate finalize kernel.
// R2/R4: window = fill(39.5 fixed) + ~26us controllable; 3 vs 2 dispatches
//     NET ZERO (=> fused-prep marginal cost ~= prep kernel + gap ~= 5us).
// R7: un-split + drop 5x5 Newton: 69.9 -> 65.4. absmax 0.
// R9: coop single-kernel FAILED absmax: plain stores not XCD-coherent.
// R10/R11: occupancy caps, LDS padding, b128, pinned regs: ALL NULL.
// R12 DIAGNOSTIC (REPS=4): delta = 20.4us -> T_compute ~= 6.8us, AT the
//     VALU issue floor. Pairs ~18 = compute 6.8 + prep-wall ~5 + ramp/tail
//     ~5 + reduce ~1. Compute was never the bottleneck; stop optimizing it.
// R13: merge TWO j-tiles per block (L0 64x128, L1 32x64): halves
//     inv-redundancy, halves per-pair prep wall, halves block count
//     (1056->544, ramp/tail down). Compute/thread doubles (at floor, scales).
//     Predict 65.0 -> 61-63us, absmax ~0. If null: REPS-ablate prep next;
//     if prep small too -> declare structural floor.
// R13-R19 bench: six acquisition timeouts + one container failure (infra).
//     Resubmitted UNCHANGED so the j-merge delta gets measured.

// paired-column triangular base: pbase(bi) = sum_{b<bi} ceil((b+1)/2)
__device__ __forceinline__ int pbase(int bi) {
    return (bi & 1) ? (((bi + 1) >> 1) * ((bi + 1) >> 1)) : ((bi * (bi + 2)) >> 2);
}
__device__ __forceinline__ void ptri_decode(int p, int& bi, int& bjp) {
    int b = (int)(2.0f * sqrtf((float)p + 0.25f));
    if (b > M0T - 1) b = M0T - 1;
    while (b + 1 <= M0T - 1 && pbase(b + 1) <= p) ++b;
    while (pbase(b) > p) --b;
    bi = b;
    bjp = p - pbase(b);
}

// normalize + adjugate inverse + 1 Newton polish, 3x3, fp32
__device__ __forceinline__ void inv3_to(const float* __restrict__ g, float* __restrict__ dst) {
    float a[9];
    float ss = 0.0f;
#pragma unroll
    for (int e = 0; e < 9; ++e) { a[e] = g[e]; ss = fmaf(a[e], a[e], ss); }
    float rn = 1.0f / (sqrtf(ss) + 1e-8f);
#pragma unroll
    for (int e = 0; e < 9; ++e) a[e] *= rn;
    float c00 = a[4] * a[8] - a[5] * a[7];
    float c01 = -(a[3] * a[8] - a[5] * a[6]);
    float c02 = a[3] * a[7] - a[4] * a[6];
    float det = a[0] * c00 + a[1] * c01 + a[2] * c02;
    float id = 1.0f / det;
    float x[9];
    x[0] = c00 * id;
    x[1] = (a[2] * a[7] - a[1] * a[8]) * id;
    x[2] = (a[1] * a[5] - a[2] * a[4]) * id;
    x[3] = c01 * id;
    x[4] = (a[0] * a[8] - a[2] * a[6]) * id;
    x[5] = (a[2] * a[3] - a[0] * a[5]) * id;
    x[6] = c02 * id;
    x[7] = (a[1] * a[6] - a[0] * a[7]) * id;
    x[8] = (a[0] * a[4] - a[1] * a[3]) * id;
    float r[9];
#pragma unroll
    for (int i = 0; i < 3; ++i)
#pragma unroll
        for (int j = 0; j < 3; ++j) {
            float m = a[i * 3 + 0] * x[0 * 3 + j];
            m = fmaf(a[i * 3 + 1], x[1 * 3 + j], m);
            m = fmaf(a[i * 3 + 2], x[2 * 3 + j], m);
            r[i * 3 + j] = ((i == j) ? 2.0f : 0.0f) - m;
        }
#pragma unroll
    for (int i = 0; i < 3; ++i)
#pragma unroll
        for (int j = 0; j < 3; ++j) {
            float m = x[i * 3 + 0] * r[0 * 3 + j];
            m = fmaf(x[i * 3 + 1], r[1 * 3 + j], m);
            m = fmaf(x[i * 3 + 2], r[2 * 3 + j], m);
            dst[i * 3 + j] = m;
        }
}

// normalize only, 3x3
__device__ __forceinline__ void norm3_to(const float* __restrict__ g, float* __restrict__ dst) {
    float a[9];
    float ss = 0.0f;
#pragma unroll
    for (int e = 0; e < 9; ++e) { a[e] = g[e]; ss = fmaf(a[e], a[e], ss); }
    float rn = 1.0f / (sqrtf(ss) + 1e-8f);
#pragma unroll
    for (int e = 0; e < 9; ++e) dst[e] = a[e] * rn;
}

// normalize + branchless GJ w/ partial pivot, 5x5, fp32 (no Newton; R7-verified)
__device__ __forceinline__ void inv5_to(const float* __restrict__ g, float* __restrict__ dst) {
    float A[5][5], B[5][5];
    float ss = 0.0f;
#pragma unroll
    for (int r = 0; r < 5; ++r)
#pragma unroll
        for (int c = 0; c < 5; ++c) {
            float v = g[r * 5 + c];
            A[r][c] = v;
            ss = fmaf(v, v, ss);
        }
    float rn = 1.0f / (sqrtf(ss) + 1e-8f);
#pragma unroll
    for (int r = 0; r < 5; ++r)
#pragma unroll
        for (int c = 0; c < 5; ++c) {
            A[r][c] *= rn;
            B[r][c] = (r == c) ? 1.0f : 0.0f;
        }
#pragma unroll
    for (int k = 0; k < 5; ++k) {
#pragma unroll
        for (int r = k + 1; r < 5; ++r) {
            bool sw = fabsf(A[r][k]) > fabsf(A[k][k]);
#pragma unroll
            for (int c = k; c < 5; ++c) {
                float Ar = A[r][c], Ak = A[k][c];
                A[r][c] = sw ? Ak : Ar;
                A[k][c] = sw ? Ar : Ak;
            }
#pragma unroll
            for (int c = 0; c < 5; ++c) {
                float Br = B[r][c], Bk = B[k][c];
                B[r][c] = sw ? Bk : Br;
                B[k][c] = sw ? Br : Bk;
            }
        }
        float piv = 1.0f / A[k][k];
#pragma unroll
        for (int c = k; c < 5; ++c) A[k][c] *= piv;
#pragma unroll
        for (int c = 0; c < 5; ++c) B[k][c] *= piv;
#pragma unroll
        for (int r = 0; r < 5; ++r) {
            if (r == k) continue;
            float f = A[r][k];
#pragma unroll
            for (int c = k; c < 5; ++c) A[r][c] = fmaf(-f, A[k][c], A[r][c]);
#pragma unroll
            for (int c = 0; c < 5; ++c) B[r][c] = fmaf(-f, B[k][c], B[r][c]);
        }
    }
#pragma unroll
    for (int r = 0; r < 5; ++r)
#pragma unroll
        for (int c = 0; c < 5; ++c) dst[r * 5 + c] = B[r][c];
}

// normalize only, 5x5
__device__ __forceinline__ void norm5_to(const float* __restrict__ g, float* __restrict__ dst) {
    float a[25];
    float ss = 0.0f;
#pragma unroll
    for (int e = 0; e < 25; ++e) { a[e] = g[e]; ss = fmaf(a[e], a[e], ss); }
    float rn = 1.0f / (sqrtf(ss) + 1e-8f);
#pragma unroll
    for (int e = 0; e < 25; ++e) dst[e] = a[e] * rn;
}

// ---------------------------------------------------------------------------
// Fused prep + pair kernel, TWO j-tiles per block.
//   blocks [0, NBP):       layer 0: 64 rows x up-to-128 cols; 4 x 4*jc /thread
//   blocks [NBP, NBTOTP):  layer 1: 32 rows x up-to-64 cols;  2 x 2*jc /thread
// Prep: L0 tid<64 inv3 (wave0); tid 64..64+64*jc norm3 (waves 1-2).
//       L1 tid<32 inv5 (wave0); tid 64..64+32*jc norm5 (wave1).
// LDS padded strides (12/28 floats, 16B) as R11; b128 reads.
// ---------------------------------------------------------------------------
__global__ __launch_bounds__(256, 4) void pairs_kernel(const float* __restrict__ k0,
                                                       const float* __restrict__ k1,
                                                       float* __restrict__ partial) {
    __shared__ __align__(16) float sA[896];   // L0: 64*12=768,  L1: 32*28=896
    __shared__ __align__(16) float sB[1792];  // L0: 128*12=1536, L1: 64*28=1792
    int tid = threadIdx.x;
    float contrib = 0.0f;

    if (blockIdx.x < NBP) {
        // ---------------- layer 0: d=3 ----------------
        int bi, bjp;
        ptri_decode(blockIdx.x, bi, bjp);
        int bj2 = 2 * bjp;
        int jc = (bj2 + 1 <= bi) ? 2 : 1;   // j-tiles covered
        int ncol = 64 * jc;

        if (tid < 64) {
            inv3_to(k0 + (bi * 64 + tid) * 9, sA + tid * 12);
        } else if (tid < 64 + ncol) {
            int j = tid - 64;
            norm3_to(k0 + ((bj2 * 64) + j) * 9, sB + j * 12);
        }
        __syncthreads();

        int ti = tid >> 4, tj = tid & 15;
        int ibase = bi * 64 + ti * 4;
        int cols_per = 4 * jc;               // 8 or 4 cols per thread
        int jbase = bj2 * 64 + tj * cols_per;
        float a[4][12];
#pragma unroll
        for (int u = 0; u < 4; ++u) {
            float4* d = (float4*)a[u];
            const float4* s = (const float4*)(sA + (ti * 4 + u) * 12);
            d[0] = s[0]; d[1] = s[1]; d[2] = s[2];
        }
        __builtin_amdgcn_sched_barrier(0);
        for (int v = 0; v < cols_per; ++v) {
            int col = tj * cols_per + v;
            float b[12];
            {
                float4* d = (float4*)b;
                const float4* s = (const float4*)(sB + col * 12);
                d[0] = s[0]; d[1] = s[1]; d[2] = s[2];
            }
#pragma unroll
            for (int u = 0; u < 4; ++u) {
                float s = 0.0f;
#pragma unroll
                for (int r = 0; r < 3; ++r)
#pragma unroll
                    for (int cc = 0; cc < 3; ++cc) {
                        float m = a[u][r * 3 + 0] * b[cc];
                        m = fmaf(a[u][r * 3 + 1], b[3 + cc], m);
                        m = fmaf(a[u][r * 3 + 2], b[6 + cc], m);
                        float d = ((r == cc) ? 1.0f : 0.0f) - m;
                        s = fmaf(d, d, s);
                    }
                bool take = ((ibase + u) > (jbase + v)) && (s < 1.0f);
                contrib += take ? (1.0f - __builtin_amdgcn_sqrtf(s)) : 0.0f;
            }
        }
    } else {
        // ---------------- layer 1: d=5 ----------------
        int bi, bjp;
        ptri_decode(blockIdx.x - NBP, bi, bjp);
        int bj2 = 2 * bjp;
        int jc = (bj2 + 1 <= bi) ? 2 : 1;
        int ncol = 32 * jc;

        if (tid < 32) {
            inv5_to(k1 + (bi * 32 + tid) * 25, sA + tid * 28);
        } else if (tid >= 64 && tid < 64 + ncol) {
            int j = tid - 64;
            norm5_to(k1 + ((bj2 * 32) + j) * 25, sB + j * 28);
        }
        __syncthreads();

        int ti = tid >> 4, tj = tid & 15;
        int ibase = bi * 32 + ti * 2;
        int cols_per = 2 * jc;               // 4 or 2 cols per thread
        int jbase = bj2 * 32 + tj * cols_per;
        float a[2][28];
#pragma unroll
        for (int u = 0; u < 2; ++u) {
            float4* d = (float4*)a[u];
            const float4* s = (const float4*)(sA + (ti * 2 + u) * 28);
#pragma unroll
            for (int q = 0; q < 7; ++q) d[q] = s[q];
        }
        __builtin_amdgcn_sched_barrier(0);
        for (int v = 0; v < cols_per; ++v) {
            int col = tj * cols_per + v;
            float b[28];
            {
                float4* d = (float4*)b;
                const float4* s = (const float4*)(sB + col * 28);
#pragma unroll
                for (int q = 0; q < 7; ++q) d[q] = s[q];
            }
#pragma unroll
            for (int u = 0; u < 2; ++u) {
                float s = 0.0f;
#pragma unroll
                for (int r = 0; r < 5; ++r)
#pragma unroll
                    for (int cc = 0; cc < 5; ++cc) {
                        float m = a[u][r * 5 + 0] * b[cc];
#pragma unroll
                        for (int k = 1; k < 5; ++k) m = fmaf(a[u][r * 5 + k], b[k * 5 + cc], m);
                        float d = ((r == cc) ? 1.0f : 0.0f) - m;
                        s = fmaf(d, d, s);
                    }
                bool take = ((ibase + u) > (jbase + v)) && (s < 1.0f);
                contrib += take ? (1.0f - __builtin_amdgcn_sqrtf(s)) : 0.0f;
            }
        }
    }

    // block reduction -> one partial per block, distinct address
#pragma unroll
    for (int off = 32; off; off >>= 1) contrib += __shfl_down(contrib, off);
    __shared__ float wsum[4];
    if ((tid & 63) == 0) wsum[tid >> 6] = contrib;
    __syncthreads();
    if (tid == 0) partial[blockIdx.x] = wsum[0] + wsum[1] + wsum[2] + wsum[3];
}

__global__ void finalize_kernel(const float* __restrict__ partial, float* __restrict__ out) {
    int tid = threadIdx.x;
    double s0 = 0.0, s1 = 0.0;
    for (int x = tid; x < NBP; x += 256) s0 += (double)partial[x];
    for (int x = NBP + tid; x < NBTOTP; x += 256) s1 += (double)partial[x];
#pragma unroll
    for (int off = 32; off; off >>= 1) {
        s0 += __shfl_down(s0, off);
        s1 += __shfl_down(s1, off);
    }
    __shared__ double w0[4], w1[4];
    if ((tid & 63) == 0) { w0[tid >> 6] = s0; w1[tid >> 6] = s1; }
    __syncthreads();
    if (tid == 0) {
        double S0 = w0[0] + w0[1] + w0[2] + w0[3];
        double S1 = w1[0] + w1[1] + w1[2] + w1[3];
        // final = (2*S0/(n0(n0-1)) + 2*S1/(n1(n1-1))) / 2
        double res = S0 / ((double)N0 * (double)(N0 - 1)) +
                     S1 / ((double)N1 * (double)(N1 - 1));
        out[0] = (float)res;
    }
}

extern "C" void kernel_launch(void* const* d_in, const int* in_sizes, int n_in,
                              void* d_out, int out_size, void* d_ws, size_t ws_size,
                              hipStream_t stream) {
    const float* k0 = (const float*)d_in[0];  // (2048,3,3)
    const float* k1 = (const float*)d_in[1];  // (1024,5,5)
    float* out = (float*)d_out;

    float* partial = (float*)d_ws;  // 544 floats

    pairs_kernel<<<NBTOTP, 256, 0, stream>>>(k0, k1, partial);
    finalize_kernel<<<1, 256, 0, stream>>>(partial, out);
}